// Round 7
// baseline (128.718 us; speedup 1.0000x reference)
//
#include <hip/hip_runtime.h>

#define V_DIM 128000
#define NV4 (V_DIM / 4)             // 32000
#define K_TOP 50
#define BLK 1024
#define NWAVE (BLK / 64)            // 16
#define CAP 1024                    // candidate cap (E[n]=173, sigma~13)
#define NBINS 2048
#define THRESH 3.0f                 // P(N(0,1)>3)=1.35e-3 -> E[n]=173 >> 50
#define STEP (BLK * 4)              // 4096 float4 per unrolled group
#define NFULL ((NV4 / STEP) * STEP) // 28672

typedef float floatx4 __attribute__((ext_vector_type(4)));

__device__ __forceinline__ unsigned key_of(float x) {
    unsigned b = __float_as_uint(x);
    return b ^ (unsigned)((((int)b) >> 31) | 0x80000000);
}
__device__ __forceinline__ float val_of(unsigned u) {
    unsigned b = u ^ (unsigned)(((~(int)u) >> 31) | 0x80000000);
    return __uint_as_float(b);
}

// pass-2 body: masked softmax write for one float4 (USE_F hoisted to template)
template <bool USE_F>
__device__ __forceinline__ void wr4(const float4 v, int j, float thrv, unsigned thr,
                                    int idxcut, float lnS, floatx4* __restrict__ o4) {
    const int i0 = 4 * j;
    bool m0, m1, m2, m3;
    if (USE_F) {
        m0 = (v.x > thrv) || (v.x == thrv && i0 <= idxcut);
        m1 = (v.y > thrv) || (v.y == thrv && i0 + 1 <= idxcut);
        m2 = (v.z > thrv) || (v.z == thrv && i0 + 2 <= idxcut);
        m3 = (v.w > thrv) || (v.w == thrv && i0 + 3 <= idxcut);
    } else {
        unsigned u0 = key_of(v.x), u1 = key_of(v.y), u2 = key_of(v.z), u3 = key_of(v.w);
        m0 = (u0 > thr) || (u0 == thr && i0 <= idxcut);
        m1 = (u1 > thr) || (u1 == thr && i0 + 1 <= idxcut);
        m2 = (u2 > thr) || (u2 == thr && i0 + 2 <= idxcut);
        m3 = (u3 > thr) || (u3 == thr && i0 + 3 <= idxcut);
    }
    floatx4 o;
    o.x = m0 ? 0.f : __expf(v.x - lnS);
    o.y = m1 ? 0.f : __expf(v.y - lnS);
    o.z = m2 ? 0.f : __expf(v.z - lnS);
    o.w = m3 ? 0.f : __expf(v.w - lnS);
    __builtin_nontemporal_store(o, &o4[j]);   // keep input L3-resident
}

template <bool USE_F>
__device__ __forceinline__ void pass2(const float4* __restrict__ x4,
                                      floatx4* __restrict__ o4, int t,
                                      float thrv, unsigned thr, int idxcut, float lnS) {
    for (int jj = 0; jj < NFULL; jj += STEP) {
        const int j0 = jj + t;
        float4 a = x4[j0];
        float4 b = x4[j0 + BLK];
        float4 c = x4[j0 + 2 * BLK];
        float4 d = x4[j0 + 3 * BLK];
        wr4<USE_F>(a, j0, thrv, thr, idxcut, lnS, o4);
        wr4<USE_F>(b, j0 + BLK, thrv, thr, idxcut, lnS, o4);
        wr4<USE_F>(c, j0 + 2 * BLK, thrv, thr, idxcut, lnS, o4);
        wr4<USE_F>(d, j0 + 3 * BLK, thrv, thr, idxcut, lnS, o4);
    }
    for (int j = NFULL + t; j < NV4; j += BLK) {
        float4 a = x4[j];
        wr4<USE_F>(a, j, thrv, thr, idxcut, lnS, o4);
    }
}

__global__ __launch_bounds__(BLK, 4)
void topk_softmax_fused(const float* __restrict__ x, float* __restrict__ out) {
    __shared__ unsigned cu_[CAP];
    __shared__ unsigned ci_[CAP];
    __shared__ unsigned hist[NBINS];    // fallback only
    __shared__ double   wsum[NWAVE];
    __shared__ double   msum[NWAVE];
    __shared__ unsigned s_cnt, s_thr, s_b1;
    __shared__ int      s_e, s_idxcut;
    __shared__ float    s_lnS;

    const int t = threadIdx.x;
    const int row = blockIdx.x;
    const float4* __restrict__ x4 = (const float4*)(x + (size_t)row * V_DIM);

    if (t == 0) s_cnt = 0;
    __syncthreads();

#define PUSH(val, idx) { unsigned p = atomicAdd(&s_cnt, 1u); if (p < CAP) { cu_[p] = key_of(val); ci_[p] = (unsigned)(idx); } }
#define COLL(v, jb) { \
        if (v.x > THRESH) PUSH(v.x, 4 * (jb)); \
        if (v.y > THRESH) PUSH(v.y, 4 * (jb) + 1); \
        if (v.z > THRESH) PUSH(v.z, 4 * (jb) + 2); \
        if (v.w > THRESH) PUSH(v.w, 4 * (jb) + 3); }

    // ---- pass 1: 4 loads in flight; 4 independent exp accumulators; collect > THRESH
    float ls0 = 0.f, ls1 = 0.f, ls2 = 0.f, ls3 = 0.f;
    for (int jj = 0; jj < NFULL; jj += STEP) {
        const int j0 = jj + t;
        float4 a = x4[j0];
        float4 b = x4[j0 + BLK];
        float4 c = x4[j0 + 2 * BLK];
        float4 d = x4[j0 + 3 * BLK];
        ls0 += __expf(a.x) + __expf(a.y) + __expf(a.z) + __expf(a.w);
        ls1 += __expf(b.x) + __expf(b.y) + __expf(b.z) + __expf(b.w);
        ls2 += __expf(c.x) + __expf(c.y) + __expf(c.z) + __expf(c.w);
        ls3 += __expf(d.x) + __expf(d.y) + __expf(d.z) + __expf(d.w);
        COLL(a, j0); COLL(b, j0 + BLK); COLL(c, j0 + 2 * BLK); COLL(d, j0 + 3 * BLK);
    }
    for (int j = NFULL + t; j < NV4; j += BLK) {
        float4 a = x4[j];
        ls0 += __expf(a.x) + __expf(a.y) + __expf(a.z) + __expf(a.w);
        COLL(a, j);
    }
    float lsum = (ls0 + ls1) + (ls2 + ls3);
    #pragma unroll
    for (int off = 32; off; off >>= 1) lsum += __shfl_down(lsum, off);
    if ((t & 63) == 0) wsum[t >> 6] = (double)lsum;   // fixed slots -> deterministic
    __syncthreads();
    unsigned n = s_cnt;

    if (n < (unsigned)K_TOP || n > (unsigned)CAP) {
        // ---- exact fallback (never taken for N(0,1)): full-row histogram select ----
        for (int i = t; i < NBINS; i += BLK) hist[i] = 0;
        if (t == 0) s_cnt = 0;
        __syncthreads();
        for (int j = t; j < NV4; j += BLK) {
            float4 v = x4[j];
            atomicAdd(&hist[key_of(v.x) >> 21], 1u);
            atomicAdd(&hist[key_of(v.y) >> 21], 1u);
            atomicAdd(&hist[key_of(v.z) >> 21], 1u);
            atomicAdd(&hist[key_of(v.w) >> 21], 1u);
        }
        __syncthreads();
        if (t == 0) {
            unsigned cum = 0; int b1 = 0;
            for (int b = NBINS - 1; b >= 0; --b) {
                if (cum + hist[b] >= (unsigned)K_TOP) { b1 = b; break; }
                cum += hist[b];
            }
            s_b1 = (unsigned)b1;
        }
        __syncthreads();
        const unsigned kmin = s_b1 << 21;    // bins >= b1 contain the whole top-K
        for (int j = t; j < NV4; j += BLK) {
            float4 v = x4[j];
            unsigned u0 = key_of(v.x), u1 = key_of(v.y), u2 = key_of(v.z), u3 = key_of(v.w);
            if (u0 >= kmin) { unsigned p = atomicAdd(&s_cnt, 1u); if (p < CAP) { cu_[p] = u0; ci_[p] = 4u * j; } }
            if (u1 >= kmin) { unsigned p = atomicAdd(&s_cnt, 1u); if (p < CAP) { cu_[p] = u1; ci_[p] = 4u * j + 1u; } }
            if (u2 >= kmin) { unsigned p = atomicAdd(&s_cnt, 1u); if (p < CAP) { cu_[p] = u2; ci_[p] = 4u * j + 2u; } }
            if (u3 >= kmin) { unsigned p = atomicAdd(&s_cnt, 1u); if (p < CAP) { cu_[p] = u3; ci_[p] = 4u * j + 3u; } }
        }
        __syncthreads();
        n = (s_cnt < (unsigned)CAP) ? s_cnt : (unsigned)CAP;
    }
    __syncthreads();

    // ---- exact rank-K select among cu_[0..n) (contains all of top-K) ----
    for (int j = t; j < (int)n; j += BLK) {
        unsigned uj = cu_[j]; int g = 0, eq = 0;
        for (int k = 0; k < (int)n; ++k) {
            unsigned uk = cu_[k];
            g += (uk > uj) ? 1 : 0;
            eq += (uk == uj) ? 1 : 0;
        }
        if (g < K_TOP && K_TOP <= g + eq) { s_thr = uj; s_e = K_TOP - g; }
    }
    __syncthreads();
    const unsigned thr = s_thr; const int e = s_e;
    // e-th smallest index among ties (jax top_k masks lowest indices first)
    for (int j = t; j < (int)n; j += BLK) {
        if (cu_[j] == thr) {
            int ij = (int)ci_[j], rank = 0;
            for (int k = 0; k < (int)n; ++k)
                rank += (cu_[k] == thr && (int)ci_[k] < ij) ? 1 : 0;
            if (rank == e - 1) s_idxcut = ij;
        }
    }
    __syncthreads();
    const int idxcut = s_idxcut;
    // masked-sum (double) and S = sum(exp) - masked
    double ms = 0.0;
    for (int j = t; j < (int)n; j += BLK) {
        unsigned u = cu_[j];
        if (u > thr || (u == thr && (int)ci_[j] <= idxcut))
            ms += exp((double)val_of(u));
    }
    #pragma unroll
    for (int off = 32; off; off >>= 1) ms += __shfl_down(ms, off);
    if ((t & 63) == 0) msum[t >> 6] = ms;
    __syncthreads();
    if (t == 0) {
        double S = 0.0;
        for (int w = 0; w < NWAVE; ++w) S += wsum[w];   // fixed order
        for (int w = 0; w < NWAVE; ++w) S -= msum[w];
        s_lnS = (float)log(S);
    }
    __syncthreads();

    // ---- pass 2: masked softmax write (L3-hot re-read, 4-deep loads, nt stores) ----
    const float lnS = s_lnS;
    const float thrv = val_of(thr);
    floatx4* __restrict__ o4 = (floatx4*)(out + (size_t)row * V_DIM);
    if (thrv != 0.0f) pass2<true>(x4, o4, t, thrv, thr, idxcut, lnS);
    else              pass2<false>(x4, o4, t, thrv, thr, idxcut, lnS);
}

extern "C" void kernel_launch(void* const* d_in, const int* in_sizes, int n_in,
                              void* d_out, int out_size, void* d_ws, size_t ws_size,
                              hipStream_t stream) {
    const float* scores = (const float*)d_in[0];
    float* out = (float*)d_out;
    const int B = in_sizes[0] / V_DIM;
    hipLaunchKernelGGL(topk_softmax_fused, dim3(B), dim3(BLK), 0, stream,
                       scores, out);
}

// Round 8
// 80.841 us; speedup vs baseline: 1.5922x; 1.5922x over previous
//
#include <hip/hip_runtime.h>

#define V_DIM 128000
#define K_TOP 50
#define CPB 8                       // chunk-blocks per row
#define CHUNK (V_DIM / CPB)         // 16000
#define CHUNK4 (CHUNK / 4)          // 4000
#define CAPB 128                    // per-chunk candidate cap (E=43.2, sigma=6.6 -> 12 sigma)
#define ROWCAP (CPB * CAPB)         // 1024
#define NBINS 2048
#define THRESH 3.0f                 // P(N(0,1)>3)=1.35e-3 -> E[row]=173 >> 50
#define NT 256                      // threads per block (4 waves)

typedef float floatx4 __attribute__((ext_vector_type(4)));

__device__ __forceinline__ unsigned key_of(float x) {
    unsigned b = __float_as_uint(x);
    return b ^ (unsigned)((((int)b) >> 31) | 0x80000000);
}
__device__ __forceinline__ float val_of(unsigned u) {
    unsigned b = u ^ (unsigned)(((~(int)u) >> 31) | 0x80000000);
    return __uint_as_float(b);
}

// ---- Kernel A: per-chunk single-pass stream: exp partial + threshold collect ----
__global__ __launch_bounds__(NT, 8)
void kA_scan(const float* __restrict__ x, uint2* __restrict__ cand,
             unsigned* __restrict__ cnts, double* __restrict__ psum) {
    __shared__ unsigned s_cnt;
    __shared__ double   wsum[NT / 64];
    const int t = threadIdx.x, bid = blockIdx.x;
    const int row = bid >> 3, ch = bid & (CPB - 1);
    const float4* __restrict__ x4 = (const float4*)(x + (size_t)row * V_DIM + ch * CHUNK);
    if (t == 0) s_cnt = 0;
    __syncthreads();
    uint2* __restrict__ my = cand + (size_t)bid * CAPB;
    const int ibase = ch * CHUNK;
    float ls = 0.f;
    for (int j = t; j < CHUNK4; j += NT) {
        float4 v = x4[j];
        ls += __expf(v.x) + __expf(v.y) + __expf(v.z) + __expf(v.w);
        if (v.x > THRESH) { unsigned p = atomicAdd(&s_cnt, 1u); if (p < CAPB) my[p] = make_uint2(key_of(v.x), (unsigned)(ibase + 4 * j)); }
        if (v.y > THRESH) { unsigned p = atomicAdd(&s_cnt, 1u); if (p < CAPB) my[p] = make_uint2(key_of(v.y), (unsigned)(ibase + 4 * j + 1)); }
        if (v.z > THRESH) { unsigned p = atomicAdd(&s_cnt, 1u); if (p < CAPB) my[p] = make_uint2(key_of(v.z), (unsigned)(ibase + 4 * j + 2)); }
        if (v.w > THRESH) { unsigned p = atomicAdd(&s_cnt, 1u); if (p < CAPB) my[p] = make_uint2(key_of(v.w), (unsigned)(ibase + 4 * j + 3)); }
    }
    #pragma unroll
    for (int off = 32; off; off >>= 1) ls += __shfl_down(ls, off);
    if ((t & 63) == 0) wsum[t >> 6] = (double)ls;   // fixed slots -> deterministic
    __syncthreads();
    if (t == 0) {
        double d = 0.0;
        for (int w = 0; w < NT / 64; ++w) d += wsum[w];
        psum[bid] = d;
        cnts[bid] = s_cnt;          // raw; kB detects overflow
    }
}

// ---- Kernel B: redundant per-row select + write own 1/8 row slice ----
__global__ __launch_bounds__(NT, 8)
void kB_select_write(const float* __restrict__ x, const uint2* __restrict__ cand,
                     const unsigned* __restrict__ cnts, const double* __restrict__ psum,
                     float* __restrict__ out) {
    __shared__ unsigned cu_[ROWCAP];
    __shared__ unsigned ci_[ROWCAP];
    __shared__ unsigned hist[NBINS];     // fallback only
    __shared__ unsigned offs[CPB + 1];
    __shared__ double   msum[NT / 64];
    __shared__ int      s_fb, s_e, s_idxcut;
    __shared__ unsigned s_thr, s_b1, s_cnt;
    __shared__ float    s_lnS;

    const int t = threadIdx.x, bid = blockIdx.x;
    const int row = bid >> 3, seg = bid & (CPB - 1);
    const int base = row * CPB;

    if (t == 0) {
        unsigned o = 0; int fb = 0;
        for (int b = 0; b < CPB; ++b) {
            unsigned c = cnts[base + b];
            if (c > CAPB) fb = 1;
            offs[b] = o;
            o += (c < CAPB ? c : CAPB);
        }
        offs[CPB] = o;
        if (o < (unsigned)K_TOP) fb = 1;
        s_fb = fb;
    }
    __syncthreads();
    unsigned n;
    if (!s_fb) {
        // gather candidates (identical order in every block of this row -> bit-identical select)
        for (int b = 0; b < CPB; ++b) {
            const unsigned o = offs[b], c = offs[b + 1] - o;
            const uint2* __restrict__ src = cand + (size_t)(base + b) * CAPB;
            for (int j = t; j < (int)c; j += NT) { uint2 e = src[j]; cu_[o + j] = e.x; ci_[o + j] = e.y; }
        }
        n = offs[CPB];
        __syncthreads();
    } else {
        // exact fallback (never taken for N(0,1)): full-row histogram select
        for (int i = t; i < NBINS; i += NT) hist[i] = 0;
        if (t == 0) s_cnt = 0;
        __syncthreads();
        const float4* __restrict__ xr = (const float4*)(x + (size_t)row * V_DIM);
        for (int j = t; j < V_DIM / 4; j += NT) {
            float4 v = xr[j];
            atomicAdd(&hist[key_of(v.x) >> 21], 1u);
            atomicAdd(&hist[key_of(v.y) >> 21], 1u);
            atomicAdd(&hist[key_of(v.z) >> 21], 1u);
            atomicAdd(&hist[key_of(v.w) >> 21], 1u);
        }
        __syncthreads();
        if (t == 0) {
            unsigned cum = 0; int b1 = 0;
            for (int b = NBINS - 1; b >= 0; --b) {
                if (cum + hist[b] >= (unsigned)K_TOP) { b1 = b; break; }
                cum += hist[b];
            }
            s_b1 = (unsigned)b1;
        }
        __syncthreads();
        const unsigned kmin = s_b1 << 21;
        for (int j = t; j < V_DIM / 4; j += NT) {
            float4 v = xr[j];
            unsigned u0 = key_of(v.x), u1 = key_of(v.y), u2 = key_of(v.z), u3 = key_of(v.w);
            if (u0 >= kmin) { unsigned p = atomicAdd(&s_cnt, 1u); if (p < ROWCAP) { cu_[p] = u0; ci_[p] = 4u * j; } }
            if (u1 >= kmin) { unsigned p = atomicAdd(&s_cnt, 1u); if (p < ROWCAP) { cu_[p] = u1; ci_[p] = 4u * j + 1u; } }
            if (u2 >= kmin) { unsigned p = atomicAdd(&s_cnt, 1u); if (p < ROWCAP) { cu_[p] = u2; ci_[p] = 4u * j + 2u; } }
            if (u3 >= kmin) { unsigned p = atomicAdd(&s_cnt, 1u); if (p < ROWCAP) { cu_[p] = u3; ci_[p] = 4u * j + 3u; } }
        }
        __syncthreads();
        n = (s_cnt < (unsigned)ROWCAP) ? s_cnt : (unsigned)ROWCAP;
        __syncthreads();
    }

    // ---- exact rank-K select among cu_[0..n) (contains all of top-K) ----
    for (int j = t; j < (int)n; j += NT) {
        unsigned uj = cu_[j]; int g = 0, eq = 0;
        for (int k = 0; k < (int)n; ++k) {
            unsigned uk = cu_[k];
            g += (uk > uj) ? 1 : 0;
            eq += (uk == uj) ? 1 : 0;
        }
        if (g < K_TOP && K_TOP <= g + eq) { s_thr = uj; s_e = K_TOP - g; }
    }
    __syncthreads();
    const unsigned thr = s_thr; const int e = s_e;
    for (int j = t; j < (int)n; j += NT) {       // e-th smallest index among ties
        if (cu_[j] == thr) {
            int ij = (int)ci_[j], rank = 0;
            for (int k = 0; k < (int)n; ++k)
                rank += (cu_[k] == thr && (int)ci_[k] < ij) ? 1 : 0;
            if (rank == e - 1) s_idxcut = ij;
        }
    }
    __syncthreads();
    const int idxcut = s_idxcut;
    double ms = 0.0;                             // masked-sum (double, fixed order)
    for (int j = t; j < (int)n; j += NT) {
        unsigned u = cu_[j];
        if (u > thr || (u == thr && (int)ci_[j] <= idxcut))
            ms += exp((double)val_of(u));
    }
    #pragma unroll
    for (int off = 32; off; off >>= 1) ms += __shfl_down(ms, off);
    if ((t & 63) == 0) msum[t >> 6] = ms;
    __syncthreads();
    if (t == 0) {
        double S = 0.0;
        for (int b = 0; b < CPB; ++b) S += psum[base + b];   // fixed order
        for (int w = 0; w < NT / 64; ++w) S -= msum[w];
        s_lnS = (float)log(S);
    }
    __syncthreads();

    // ---- write own 1/8 row slice: masked softmax, contiguous nt stores ----
    const float lnS = s_lnS;
    const float thrv = val_of(thr);
    const bool use_f = (thrv != 0.0f);           // uniform; +-0 uses key compare
    const float4* __restrict__ xs = (const float4*)(x + (size_t)row * V_DIM + seg * CHUNK);
    floatx4* __restrict__ o4 = (floatx4*)(out + (size_t)row * V_DIM + seg * CHUNK);
    const int ib = seg * CHUNK;
    for (int j = t; j < CHUNK4; j += NT) {
        float4 v = xs[j];
        const int i0 = ib + 4 * j;
        bool m0, m1, m2, m3;
        if (use_f) {
            m0 = (v.x > thrv) || (v.x == thrv && i0 <= idxcut);
            m1 = (v.y > thrv) || (v.y == thrv && i0 + 1 <= idxcut);
            m2 = (v.z > thrv) || (v.z == thrv && i0 + 2 <= idxcut);
            m3 = (v.w > thrv) || (v.w == thrv && i0 + 3 <= idxcut);
        } else {
            unsigned u0 = key_of(v.x), u1 = key_of(v.y), u2 = key_of(v.z), u3 = key_of(v.w);
            m0 = (u0 > thr) || (u0 == thr && i0 <= idxcut);
            m1 = (u1 > thr) || (u1 == thr && i0 + 1 <= idxcut);
            m2 = (u2 > thr) || (u2 == thr && i0 + 2 <= idxcut);
            m3 = (u3 > thr) || (u3 == thr && i0 + 3 <= idxcut);
        }
        floatx4 o;
        o.x = m0 ? 0.f : __expf(v.x - lnS);
        o.y = m1 ? 0.f : __expf(v.y - lnS);
        o.z = m2 ? 0.f : __expf(v.z - lnS);
        o.w = m3 ? 0.f : __expf(v.w - lnS);
        __builtin_nontemporal_store(o, &o4[j]);  // keep input L3-resident
    }
}

extern "C" void kernel_launch(void* const* d_in, const int* in_sizes, int n_in,
                              void* d_out, int out_size, void* d_ws, size_t ws_size,
                              hipStream_t stream) {
    const float* scores = (const float*)d_in[0];
    float* out = (float*)d_out;
    const int B = in_sizes[0] / V_DIM;
    const int NBLK = B * CPB;

    char* wsb = (char*)d_ws;
    uint2*    cand = (uint2*)wsb;                          // NBLK*CAPB*8 B = 2 MB @ B=256
    size_t off = (size_t)NBLK * CAPB * sizeof(uint2);
    unsigned* cnts = (unsigned*)(wsb + off);               // NBLK*4 B
    off += (size_t)NBLK * sizeof(unsigned);
    off = (off + 15) & ~(size_t)15;
    double*   psum = (double*)(wsb + off);                 // NBLK*8 B

    hipLaunchKernelGGL(kA_scan, dim3(NBLK), dim3(NT), 0, stream,
                       scores, cand, cnts, psum);
    hipLaunchKernelGGL(kB_select_write, dim3(NBLK), dim3(NT), 0, stream,
                       scores, cand, cnts, psum, out);
}

// Round 9
// 72.657 us; speedup vs baseline: 1.7716x; 1.1126x over previous
//
#include <hip/hip_runtime.h>

#define V_DIM 128000
#define NV4 (V_DIM / 4)             // 32000
#define K_TOP 50
#define BLK 1024
#define NWAVE (BLK / 64)            // 16
#define CAP 1024                    // candidate cap (E[n]=173, sigma~13)
#define NBINS 2048
#define THRESH 3.0f                 // P(N(0,1)>3)=1.35e-3 -> E[n]=173 >> 50

typedef float floatx4 __attribute__((ext_vector_type(4)));

__device__ __forceinline__ unsigned key_of(float x) {
    unsigned b = __float_as_uint(x);
    return b ^ (unsigned)((((int)b) >> 31) | 0x80000000);
}
__device__ __forceinline__ float val_of(unsigned u) {
    unsigned b = u ^ (unsigned)(((~(int)u) >> 31) | 0x80000000);
    return __uint_as_float(b);
}

// pass-2 body: masked softmax write for one float4 (USE_F hoisted to template)
template <bool USE_F>
__device__ __forceinline__ void wr4(const float4 v, int j, float thrv, unsigned thr,
                                    int idxcut, float lnS, floatx4* __restrict__ o4) {
    const int i0 = 4 * j;
    bool m0, m1, m2, m3;
    if (USE_F) {
        m0 = (v.x > thrv) || (v.x == thrv && i0 <= idxcut);
        m1 = (v.y > thrv) || (v.y == thrv && i0 + 1 <= idxcut);
        m2 = (v.z > thrv) || (v.z == thrv && i0 + 2 <= idxcut);
        m3 = (v.w > thrv) || (v.w == thrv && i0 + 3 <= idxcut);
    } else {
        unsigned u0 = key_of(v.x), u1 = key_of(v.y), u2 = key_of(v.z), u3 = key_of(v.w);
        m0 = (u0 > thr) || (u0 == thr && i0 <= idxcut);
        m1 = (u1 > thr) || (u1 == thr && i0 + 1 <= idxcut);
        m2 = (u2 > thr) || (u2 == thr && i0 + 2 <= idxcut);
        m3 = (u3 > thr) || (u3 == thr && i0 + 3 <= idxcut);
    }
    floatx4 o;
    o.x = m0 ? 0.f : __expf(v.x - lnS);
    o.y = m1 ? 0.f : __expf(v.y - lnS);
    o.z = m2 ? 0.f : __expf(v.z - lnS);
    o.w = m3 ? 0.f : __expf(v.w - lnS);
    __builtin_nontemporal_store(o, &o4[j]);   // keep input L3-resident
}

// depth-2 pipelined pass 2: one contiguous store stream, next load issued early
template <bool USE_F>
__device__ __forceinline__ void pass2(const float4* __restrict__ x4,
                                      floatx4* __restrict__ o4, int t,
                                      float thrv, unsigned thr, int idxcut, float lnS) {
    int j = t;
    float4 cur = x4[j];
    for (; j + BLK < NV4; j += BLK) {
        float4 nxt = x4[j + BLK];         // in flight while cur is processed
        wr4<USE_F>(cur, j, thrv, thr, idxcut, lnS, o4);
        cur = nxt;
    }
    wr4<USE_F>(cur, j, thrv, thr, idxcut, lnS, o4);
}

__global__ __launch_bounds__(BLK, 1)
void topk_softmax_fused(const float* __restrict__ x, float* __restrict__ out) {
    __shared__ unsigned cu_[CAP];
    __shared__ unsigned ci_[CAP];
    __shared__ unsigned hist[NBINS];    // fallback only
    __shared__ double   wsum[NWAVE];
    __shared__ double   msum[NWAVE];
    __shared__ unsigned s_cnt, s_thr, s_b1;
    __shared__ int      s_e, s_idxcut;
    __shared__ float    s_lnS;

    const int t = threadIdx.x;
    const int row = blockIdx.x;
    const float4* __restrict__ x4 = (const float4*)(x + (size_t)row * V_DIM);

    if (t == 0) s_cnt = 0;
    __syncthreads();

#define PUSH(val, idx) { unsigned p = atomicAdd(&s_cnt, 1u); if (p < CAP) { cu_[p] = key_of(val); ci_[p] = (unsigned)(idx); } }
#define COLL(v, jb) { \
        if (v.x > THRESH) PUSH(v.x, 4 * (jb)); \
        if (v.y > THRESH) PUSH(v.y, 4 * (jb) + 1); \
        if (v.z > THRESH) PUSH(v.z, 4 * (jb) + 2); \
        if (v.w > THRESH) PUSH(v.w, 4 * (jb) + 3); }
#define PROC1(v, jb) { \
        ls0 += __expf(v.x) + __expf(v.y); \
        ls1 += __expf(v.z) + __expf(v.w); \
        COLL(v, jb); }

    // ---- pass 1 (depth-2 pipelined): exp partial + collect candidates > THRESH ----
    float ls0 = 0.f, ls1 = 0.f;
    {
        int j = t;
        float4 cur = x4[j];
        for (; j + BLK < NV4; j += BLK) {
            float4 nxt = x4[j + BLK];     // in flight while cur is processed
            PROC1(cur, j);
            cur = nxt;
        }
        PROC1(cur, j);
    }
    float lsum = ls0 + ls1;
    #pragma unroll
    for (int off = 32; off; off >>= 1) lsum += __shfl_down(lsum, off);
    if ((t & 63) == 0) wsum[t >> 6] = (double)lsum;   // fixed slots -> deterministic
    __syncthreads();
    unsigned n = s_cnt;

    if (n < (unsigned)K_TOP || n > (unsigned)CAP) {
        // ---- exact fallback (never taken for N(0,1)): full-row histogram select ----
        for (int i = t; i < NBINS; i += BLK) hist[i] = 0;
        if (t == 0) s_cnt = 0;
        __syncthreads();
        for (int j = t; j < NV4; j += BLK) {
            float4 v = x4[j];
            atomicAdd(&hist[key_of(v.x) >> 21], 1u);
            atomicAdd(&hist[key_of(v.y) >> 21], 1u);
            atomicAdd(&hist[key_of(v.z) >> 21], 1u);
            atomicAdd(&hist[key_of(v.w) >> 21], 1u);
        }
        __syncthreads();
        if (t == 0) {
            unsigned cum = 0; int b1 = 0;
            for (int b = NBINS - 1; b >= 0; --b) {
                if (cum + hist[b] >= (unsigned)K_TOP) { b1 = b; break; }
                cum += hist[b];
            }
            s_b1 = (unsigned)b1;
        }
        __syncthreads();
        const unsigned kmin = s_b1 << 21;    // bins >= b1 contain the whole top-K
        for (int j = t; j < NV4; j += BLK) {
            float4 v = x4[j];
            unsigned u0 = key_of(v.x), u1 = key_of(v.y), u2 = key_of(v.z), u3 = key_of(v.w);
            if (u0 >= kmin) { unsigned p = atomicAdd(&s_cnt, 1u); if (p < CAP) { cu_[p] = u0; ci_[p] = 4u * j; } }
            if (u1 >= kmin) { unsigned p = atomicAdd(&s_cnt, 1u); if (p < CAP) { cu_[p] = u1; ci_[p] = 4u * j + 1u; } }
            if (u2 >= kmin) { unsigned p = atomicAdd(&s_cnt, 1u); if (p < CAP) { cu_[p] = u2; ci_[p] = 4u * j + 2u; } }
            if (u3 >= kmin) { unsigned p = atomicAdd(&s_cnt, 1u); if (p < CAP) { cu_[p] = u3; ci_[p] = 4u * j + 3u; } }
        }
        __syncthreads();
        n = (s_cnt < (unsigned)CAP) ? s_cnt : (unsigned)CAP;
    }
    __syncthreads();

    // ---- exact rank-K select among cu_[0..n) (contains all of top-K) ----
    for (int j = t; j < (int)n; j += BLK) {
        unsigned uj = cu_[j]; int g = 0, eq = 0;
        for (int k = 0; k < (int)n; ++k) {
            unsigned uk = cu_[k];
            g += (uk > uj) ? 1 : 0;
            eq += (uk == uj) ? 1 : 0;
        }
        if (g < K_TOP && K_TOP <= g + eq) { s_thr = uj; s_e = K_TOP - g; }
    }
    __syncthreads();
    const unsigned thr = s_thr; const int e = s_e;
    // e-th smallest index among ties (jax top_k masks lowest indices first)
    for (int j = t; j < (int)n; j += BLK) {
        if (cu_[j] == thr) {
            int ij = (int)ci_[j], rank = 0;
            for (int k = 0; k < (int)n; ++k)
                rank += (cu_[k] == thr && (int)ci_[k] < ij) ? 1 : 0;
            if (rank == e - 1) s_idxcut = ij;
        }
    }
    __syncthreads();
    const int idxcut = s_idxcut;
    // masked-sum (double) and S = sum(exp) - masked
    double ms = 0.0;
    for (int j = t; j < (int)n; j += BLK) {
        unsigned u = cu_[j];
        if (u > thr || (u == thr && (int)ci_[j] <= idxcut))
            ms += exp((double)val_of(u));
    }
    #pragma unroll
    for (int off = 32; off; off >>= 1) ms += __shfl_down(ms, off);
    if ((t & 63) == 0) msum[t >> 6] = ms;
    __syncthreads();
    if (t == 0) {
        double S = 0.0;
        for (int w = 0; w < NWAVE; ++w) S += wsum[w];   // fixed order
        for (int w = 0; w < NWAVE; ++w) S -= msum[w];
        s_lnS = (float)log(S);
    }
    __syncthreads();

    // ---- pass 2: masked softmax write (depth-2 pipelined, nt stores) ----
    const float lnS = s_lnS;
    const float thrv = val_of(thr);
    floatx4* __restrict__ o4 = (floatx4*)(out + (size_t)row * V_DIM);
    if (thrv != 0.0f) pass2<true>(x4, o4, t, thrv, thr, idxcut, lnS);
    else              pass2<false>(x4, o4, t, thrv, thr, idxcut, lnS);
}

extern "C" void kernel_launch(void* const* d_in, const int* in_sizes, int n_in,
                              void* d_out, int out_size, void* d_ws, size_t ws_size,
                              hipStream_t stream) {
    const float* scores = (const float*)d_in[0];
    float* out = (float*)d_out;
    const int B = in_sizes[0] / V_DIM;
    hipLaunchKernelGGL(topk_softmax_fused, dim3(B), dim3(BLK), 0, stream,
                       scores, out);
}